// Round 5
// baseline (313.135 us; speedup 1.0000x reference)
//
#include <hip/hip_runtime.h>
#include <hip/hip_bf16.h>
#include <stdint.h>

#define B_ 4
#define T_ 2048
#define D_ 1024
#define H_ 16
#define HD_ 64
#define M_TOT (B_ * T_)   // 8192

typedef unsigned short u16t;
typedef __bf16 bf16x4 __attribute__((ext_vector_type(4)));
typedef __bf16 bf16x8 __attribute__((ext_vector_type(8)));
typedef float f32x4 __attribute__((ext_vector_type(4)));

__device__ __forceinline__ u16t f2bf(float f) {
    union { float f; uint32_t u; } x; x.f = f;
    uint32_t r = x.u + 0x7fffu + ((x.u >> 16) & 1u);
    return (u16t)(r >> 16);
}

// async global -> LDS, 16B per lane; lds dest is wave-uniform base (+ lane*16 by HW)
__device__ __forceinline__ void gload16(const void* g, void* l) {
    __builtin_amdgcn_global_load_lds((const __attribute__((address_space(1))) void*)g,
                                     (__attribute__((address_space(3))) void*)l, 16, 0, 0);
}

// ---------------- convert x (fp32 -> bf16), 8 elems/thread ----------------
__global__ __launch_bounds__(256) void cvt_bf16_kernel(const float* __restrict__ in,
                                                       u16t* __restrict__ out, int n8) {
    int i = blockIdx.x * 256 + threadIdx.x;
    if (i >= n8) return;
    const float4* p = (const float4*)in + (size_t)i * 2;
    float4 a = p[0], b = p[1];
    u16t o[8] = {f2bf(a.x), f2bf(a.y), f2bf(a.z), f2bf(a.w),
                 f2bf(b.x), f2bf(b.y), f2bf(b.z), f2bf(b.w)};
    *(uint4*)(out + (size_t)i * 8) = *(const uint4*)o;
}

// ------------- transpose + convert W[k][n] fp32 -> Wt[n][k] bf16 -------------
__global__ __launch_bounds__(256) void transp_kernel(const float* __restrict__ W0,
                                                     const float* __restrict__ W1,
                                                     const float* __restrict__ W2,
                                                     const float* __restrict__ W3,
                                                     u16t* __restrict__ T0,
                                                     u16t* __restrict__ T1,
                                                     u16t* __restrict__ T2,
                                                     u16t* __restrict__ T3) {
    __shared__ u16t tile[64][65];
    const float* W; u16t* To;
    switch (blockIdx.z) {
        case 0: W = W0; To = T0; break;
        case 1: W = W1; To = T1; break;
        case 2: W = W2; To = T2; break;
        default: W = W3; To = T3; break;
    }
    int n0 = blockIdx.x * 64, k0 = blockIdx.y * 64;
    int t = threadIdx.x;
#pragma unroll
    for (int i = 0; i < 16; ++i) {
        int idx = i * 256 + t;
        int r = idx >> 6, c = idx & 63;
        tile[r][c] = f2bf(W[(size_t)(k0 + r) * D_ + n0 + c]);
    }
    __syncthreads();
#pragma unroll
    for (int i = 0; i < 16; ++i) {
        int idx = i * 256 + t;
        int r = idx >> 6, c = idx & 63;
        To[(size_t)(n0 + r) * D_ + k0 + c] = tile[c][r];
    }
}

// ---------------- bf16 GEMM (m97 structure: global_load_lds staging, linear LDS) ----
// MODE 0: bf16 row-major out. MODE 1: f32 row-major out. MODE 2: bf16 Vt[b][h][hd][t] out.
template <int MODE>
__global__ __launch_bounds__(256) void gemm_bf16_kernel(const u16t* __restrict__ A,
                                                        const u16t* __restrict__ Wt,
                                                        const float* __restrict__ bias,
                                                        void* __restrict__ outp,
                                                        float scale) {
    __shared__ u16t As[128 * 64];
    __shared__ u16t Bs[128 * 64];
    const int t = threadIdx.x;
    const int lane = t & 63, w = t >> 6;
    const int wm = w >> 1, wn = w & 1;
    const int l15 = lane & 15, l4 = lane >> 4;
    const int m0 = blockIdx.x * 128, n0 = blockIdx.y * 128;
    const int K = D_, N = D_;

    f32x4 acc[4][4] = {};

    for (int k0 = 0; k0 < K; k0 += 64) {
#pragma unroll
        for (int i = 0; i < 4; ++i) {
            int lin = i * 256 + t;
            int r = lin >> 3, c = (lin & 7) * 8;
            int ldsoff = (i * 256 + w * 64) * 8;   // wave-uniform, u16 units
            gload16(&A[(size_t)(m0 + r) * K + k0 + c], &As[ldsoff]);
            gload16(&Wt[(size_t)(n0 + r) * K + k0 + c], &Bs[ldsoff]);
        }
        __syncthreads();   // drains vmcnt -> staged data visible
#pragma unroll
        for (int ks = 0; ks < 64; ks += 32) {
            bf16x8 af[4], bf[4];
#pragma unroll
            for (int i = 0; i < 4; ++i) {
                af[i] = *(const bf16x8*)&As[(wm * 64 + i * 16 + l15) * 64 + ks + l4 * 8];
                bf[i] = *(const bf16x8*)&Bs[(wn * 64 + i * 16 + l15) * 64 + ks + l4 * 8];
            }
#pragma unroll
            for (int mi = 0; mi < 4; ++mi)
#pragma unroll
                for (int ni = 0; ni < 4; ++ni)
                    acc[mi][ni] = __builtin_amdgcn_mfma_f32_16x16x32_bf16(
                        af[mi], bf[ni], acc[mi][ni], 0, 0, 0);
        }
        __syncthreads();
    }

#pragma unroll
    for (int mi = 0; mi < 4; ++mi) {
#pragma unroll
        for (int ni = 0; ni < 4; ++ni) {
            int col = n0 + wn * 64 + ni * 16 + l15;
            float bn = bias[col];
            if (MODE == 2) {
                int token0 = m0 + wm * 64 + mi * 16 + l4 * 4;
                u16t o4[4];
#pragma unroll
                for (int r = 0; r < 4; ++r) o4[r] = f2bf(acc[mi][ni][r] + bn);
                int b = token0 >> 11, tb = token0 & (T_ - 1);
                int h = col >> 6, hd = col & 63;
                *(uint2*)&((u16t*)outp)[(((size_t)b * H_ + h) * HD_ + hd) * T_ + tb] =
                    *(const uint2*)o4;
            } else {
#pragma unroll
                for (int r = 0; r < 4; ++r) {
                    int row = m0 + wm * 64 + mi * 16 + l4 * 4 + r;
                    float v = (acc[mi][ni][r] + bn) * scale;
                    if (MODE == 1) ((float*)outp)[(size_t)row * N + col] = v;
                    else           ((u16t*)outp)[(size_t)row * N + col] = f2bf(v);
                }
            }
        }
    }
}

// ---------------- causal flash attention ----------------
// Double-buffered global_load_lds staging (zero staging registers), XOR-swizzled
// LDS (pre-swizzled global source + swizzled reads; rule #21). Sequential q-subtile
// softmax (scoped accs[4]) keeps peak live VGPRs ~100 -> no scratch spill.
// Softmax in base-2 domain (log2e folded into Q scale).
__global__ __launch_bounds__(256, 4) void attn_kernel(const u16t* __restrict__ Q,
                                                      const u16t* __restrict__ K,
                                                      const u16t* __restrict__ Vt,
                                                      u16t* __restrict__ O) {
    __shared__ u16t Ks[2][64 * 64];
    __shared__ u16t Vs[2][64 * 64];   // Vs[d][kv], swizzled

    const int t = threadIdx.x;
    const int lane = t & 63, w = t >> 6;
    const int l15 = lane & 15, l4 = lane >> 4;

    const int lin = blockIdx.y * 16 + blockIdx.x;
    const int kk = lin >> 8;
    const int jb = (lin >> 4) & 15, jx = lin & 15;
    const int bh = kk * 16 + jb;
    const int qtile = (kk & 1) ? (15 - jx) : jx;

    const size_t base = (size_t)(bh >> 4) * T_ * D_ + (size_t)(bh & 15) * HD_;
    const size_t vtbase = (size_t)bh * HD_ * T_;
    const int q0 = qtile * 128;
    const int qsub0 = q0 + w * 32;
    const int sw = l15 & 7;            // read-side XOR (row & 7)

    // staging: linear LDS dest; global source pre-swizzled with c16 ^= row&7
    auto stage = [&](int jt, int bufsel) {
#pragma unroll
        for (int c = 0; c < 2; ++c) {
            int i = c * 256 + t;
            int r = i >> 3, c16 = i & 7;
            int g16 = c16 ^ (r & 7);
            int ldsoff = (c * 256 + w * 64) * 8;   // u16 units, wave-uniform
            gload16(&K[base + (size_t)(jt * 64 + r) * D_ + g16 * 8], &Ks[bufsel][ldsoff]);
            gload16(&Vt[vtbase + (size_t)r * T_ + jt * 64 + g16 * 8], &Vs[bufsel][ldsoff]);
        }
    };

    bf16x8 qf[2][2];
#pragma unroll
    for (int qa = 0; qa < 2; ++qa) {
        const u16t* qp = &Q[base + (size_t)(qsub0 + qa * 16 + l15) * D_];
        qf[qa][0] = *(const bf16x8*)&qp[l4 * 8];
        qf[qa][1] = *(const bf16x8*)&qp[32 + l4 * 8];
    }

    f32x4 acc_o[2][4] = {};
    float mrun[2] = {-1e30f, -1e30f};
    float lrun[2] = {0.f, 0.f};

    const int njt = 2 * qtile + 2;
    stage(0, 0);

    for (int jt = 0; jt < njt; ++jt) {
        const int cur = jt & 1;
        const int kv0 = jt * 64;
        __syncthreads();                 // drains vmcnt: buf[cur] ready; guards buf reuse
        if (jt + 1 < njt) stage(jt + 1, cur ^ 1);

        if (kv0 <= qsub0 + 31) {         // skip fully-masked tail tiles (waves 0/1)
            const u16t* kb = Ks[cur];
            const u16t* vb = Vs[cur];

            bf16x8 pa[2][2];
#pragma unroll
            for (int qa = 0; qa < 2; ++qa) {
                f32x4 accs[4] = {};      // scoped: 16 VGPRs, reused across qa
#pragma unroll
                for (int mt = 0; mt < 4; ++mt) {
                    const u16t* kr = &kb[(mt * 16 + l15) * 64];
                    bf16x8 kf0 = *(const bf16x8*)&kr[(l4 ^ sw) * 8];
                    bf16x8 kf1 = *(const bf16x8*)&kr[((4 + l4) ^ sw) * 8];
                    accs[mt] = __builtin_amdgcn_mfma_f32_16x16x32_bf16(kf0, qf[qa][0], accs[mt], 0, 0, 0);
                    accs[mt] = __builtin_amdgcn_mfma_f32_16x16x32_bf16(kf1, qf[qa][1], accs[mt], 0, 0, 0);
                }

                const int qrow = qsub0 + qa * 16 + l15;
                if (kv0 + 63 > qsub0 + qa * 16) {   // diagonal-touching: causal mask
#pragma unroll
                    for (int mt = 0; mt < 4; ++mt)
#pragma unroll
                        for (int r = 0; r < 4; ++r)
                            if (kv0 + mt * 16 + l4 * 4 + r > qrow) accs[mt][r] = -1e30f;
                }

                float pmax = -1e30f;
#pragma unroll
                for (int mt = 0; mt < 4; ++mt)
#pragma unroll
                    for (int r = 0; r < 4; ++r) pmax = fmaxf(pmax, accs[mt][r]);
                pmax = fmaxf(pmax, __shfl_xor(pmax, 16));
                pmax = fmaxf(pmax, __shfl_xor(pmax, 32));

                // defer-rescale (THR=0, exact), base-2 domain
                if (!__all(pmax <= mrun[qa])) {
                    float mnew = fmaxf(mrun[qa], pmax);
                    float corr = exp2f(mrun[qa] - mnew);
                    lrun[qa] *= corr;
                    mrun[qa] = mnew;
#pragma unroll
                    for (int r = 0; r < 4; ++r) {
                        float f = __shfl(corr, l4 * 4 + r);
#pragma unroll
                        for (int nt = 0; nt < 4; ++nt) acc_o[qa][nt][r] *= f;
                    }
                }

                const float m = mrun[qa];
                float sm[4];
#pragma unroll
                for (int mt = 0; mt < 4; ++mt) {
                    float s = 0.f;
#pragma unroll
                    for (int r = 0; r < 4; ++r) {
                        float p = exp2f(accs[mt][r] - m);
                        s += p;
                        pa[qa][mt >> 1][(mt & 1) * 4 + r] = (__bf16)p;   // k-slot pi mapping
                    }
                    sm[mt] = s;
                }
                float psum = (sm[0] + sm[1]) + (sm[2] + sm[3]);
                psum += __shfl_xor(psum, 16);
                psum += __shfl_xor(psum, 32);
                lrun[qa] += psum;
            }

            // PV, k-slot permutation pi_s(l4,j) = 32s + (j>=4?16:0) + l4*4 + (j&3)
#pragma unroll
            for (int s = 0; s < 2; ++s) {
#pragma unroll
                for (int nt = 0; nt < 4; ++nt) {
                    const u16t* vr = &vb[(nt * 16 + l15) * 64];
                    int o1 = s * 32 + l4 * 4, o2 = o1 + 16;
                    bf16x4 v0 = *(const bf16x4*)&vr[(((o1 >> 3) ^ sw) << 3) | (o1 & 7)];
                    bf16x4 v1 = *(const bf16x4*)&vr[(((o2 >> 3) ^ sw) << 3) | (o2 & 7)];
                    bf16x8 vf = __builtin_shufflevector(v0, v1, 0, 1, 2, 3, 4, 5, 6, 7);
                    acc_o[0][nt] = __builtin_amdgcn_mfma_f32_16x16x32_bf16(pa[0][s], vf, acc_o[0][nt], 0, 0, 0);
                    acc_o[1][nt] = __builtin_amdgcn_mfma_f32_16x16x32_bf16(pa[1][s], vf, acc_o[1][nt], 0, 0, 0);
                }
            }
        }
    }

    // finalize: divide by l, store bf16
#pragma unroll
    for (int qa = 0; qa < 2; ++qa)
#pragma unroll
        for (int r = 0; r < 4; ++r) {
            float li = __shfl(lrun[qa], l4 * 4 + r);
            float inv = 1.f / li;
            int row = qsub0 + qa * 16 + l4 * 4 + r;
#pragma unroll
            for (int nt = 0; nt < 4; ++nt)
                O[base + (size_t)row * D_ + nt * 16 + l15] = f2bf(acc_o[qa][nt][r] * inv);
        }
}

extern "C" void kernel_launch(void* const* d_in, const int* in_sizes, int n_in,
                              void* d_out, int out_size, void* d_ws, size_t ws_size,
                              hipStream_t stream) {
    const float* x  = (const float*)d_in[0];
    const float* Wq = (const float*)d_in[1];
    const float* bq = (const float*)d_in[2];
    const float* Wk = (const float*)d_in[3];
    const float* bk = (const float*)d_in[4];
    const float* Wv = (const float*)d_in[5];
    const float* bv = (const float*)d_in[6];
    const float* Wp = (const float*)d_in[7];
    const float* bp = (const float*)d_in[8];
    float* out = (float*)d_out;

    u16t* ws = (u16t*)d_ws;
    const size_t XN = (size_t)M_TOT * D_;      // 8M elems
    u16t* xb  = ws;                            // x bf16; reused as attn output O
    u16t* q   = ws + XN;
    u16t* k   = ws + 2 * XN;
    u16t* vt  = ws + 3 * XN;                   // Vt[b][h][hd][t] (written by V-GEMM epilogue)
    u16t* wtq = ws + 4 * XN;
    u16t* wtk = wtq + (size_t)D_ * D_;
    u16t* wtv = wtk + (size_t)D_ * D_;
    u16t* wtp = wtv + (size_t)D_ * D_;
    u16t* o   = xb;                            // attn output reuses xb (dead after GEMMs)

    cvt_bf16_kernel<<<(int)(XN / 8 / 256), 256, 0, stream>>>(x, xb, (int)(XN / 8));
    transp_kernel<<<dim3(16, 16, 4), 256, 0, stream>>>(Wq, Wk, Wv, Wp, wtq, wtk, wtv, wtp);

    dim3 ggrid(M_TOT / 128, D_ / 128);
    // Q scale folds 1/sqrt(HD) * log2(e): softmax runs in base-2 domain
    gemm_bf16_kernel<0><<<ggrid, 256, 0, stream>>>(xb, wtq, bq, q, 0.125f * 1.44269504088896f);
    gemm_bf16_kernel<0><<<ggrid, 256, 0, stream>>>(xb, wtk, bk, k, 1.0f);
    gemm_bf16_kernel<2><<<ggrid, 256, 0, stream>>>(xb, wtv, bv, vt, 1.0f);  // fused V-transpose

    attn_kernel<<<dim3(16, 64), 256, 0, stream>>>(q, k, vt, o);

    gemm_bf16_kernel<1><<<ggrid, 256, 0, stream>>>(o, wtp, bp, out, 1.0f);
}

// Round 6
// 241.646 us; speedup vs baseline: 1.2958x; 1.2958x over previous
//
#include <hip/hip_runtime.h>
#include <hip/hip_bf16.h>
#include <stdint.h>

#define B_ 4
#define T_ 2048
#define D_ 1024
#define H_ 16
#define HD_ 64
#define M_TOT (B_ * T_)   // 8192

typedef unsigned short u16t;
typedef __bf16 bf16x4 __attribute__((ext_vector_type(4)));
typedef __bf16 bf16x8 __attribute__((ext_vector_type(8)));
typedef float f32x4 __attribute__((ext_vector_type(4)));

__device__ __forceinline__ u16t f2bf(float f) {
    union { float f; uint32_t u; } x; x.f = f;
    uint32_t r = x.u + 0x7fffu + ((x.u >> 16) & 1u);
    return (u16t)(r >> 16);
}

// async global -> LDS, 16B per lane; lds dest is wave-uniform base (+ lane*16 by HW)
__device__ __forceinline__ void gload16(const void* g, void* l) {
    __builtin_amdgcn_global_load_lds((const __attribute__((address_space(1))) void*)g,
                                     (__attribute__((address_space(3))) void*)l, 16, 0, 0);
}

// ---------------- convert x (fp32 -> bf16), 8 elems/thread ----------------
__global__ __launch_bounds__(256) void cvt_bf16_kernel(const float* __restrict__ in,
                                                       u16t* __restrict__ out, int n8) {
    int i = blockIdx.x * 256 + threadIdx.x;
    if (i >= n8) return;
    const float4* p = (const float4*)in + (size_t)i * 2;
    float4 a = p[0], b = p[1];
    u16t o[8] = {f2bf(a.x), f2bf(a.y), f2bf(a.z), f2bf(a.w),
                 f2bf(b.x), f2bf(b.y), f2bf(b.z), f2bf(b.w)};
    *(uint4*)(out + (size_t)i * 8) = *(const uint4*)o;
}

// ------------- transpose + convert W[k][n] fp32 -> Wt[n][k] bf16 -------------
__global__ __launch_bounds__(256) void transp_kernel(const float* __restrict__ W0,
                                                     const float* __restrict__ W1,
                                                     const float* __restrict__ W2,
                                                     const float* __restrict__ W3,
                                                     u16t* __restrict__ T0,
                                                     u16t* __restrict__ T1,
                                                     u16t* __restrict__ T2,
                                                     u16t* __restrict__ T3) {
    __shared__ u16t tile[64][65];
    const float* W; u16t* To;
    switch (blockIdx.z) {
        case 0: W = W0; To = T0; break;
        case 1: W = W1; To = T1; break;
        case 2: W = W2; To = T2; break;
        default: W = W3; To = T3; break;
    }
    int n0 = blockIdx.x * 64, k0 = blockIdx.y * 64;
    int t = threadIdx.x;
#pragma unroll
    for (int i = 0; i < 16; ++i) {
        int idx = i * 256 + t;
        int r = idx >> 6, c = idx & 63;
        tile[r][c] = f2bf(W[(size_t)(k0 + r) * D_ + n0 + c]);
    }
    __syncthreads();
#pragma unroll
    for (int i = 0; i < 16; ++i) {
        int idx = i * 256 + t;
        int r = idx >> 6, c = idx & 63;
        To[(size_t)(n0 + r) * D_ + k0 + c] = tile[c][r];
    }
}

// ---------------- bf16 GEMM (m97 structure: global_load_lds staging, linear LDS) ----
// MODE 0: bf16 row-major out. MODE 1: f32 row-major out. MODE 2: bf16 Vt[b][h][hd][t] out.
template <int MODE>
__global__ __launch_bounds__(256) void gemm_bf16_kernel(const u16t* __restrict__ A,
                                                        const u16t* __restrict__ Wt,
                                                        const float* __restrict__ bias,
                                                        void* __restrict__ outp,
                                                        float scale) {
    __shared__ u16t As[128 * 64];
    __shared__ u16t Bs[128 * 64];
    const int t = threadIdx.x;
    const int lane = t & 63, w = t >> 6;
    const int wm = w >> 1, wn = w & 1;
    const int l15 = lane & 15, l4 = lane >> 4;
    const int m0 = blockIdx.x * 128, n0 = blockIdx.y * 128;
    const int K = D_, N = D_;

    f32x4 acc[4][4] = {};

    for (int k0 = 0; k0 < K; k0 += 64) {
#pragma unroll
        for (int i = 0; i < 4; ++i) {
            int lin = i * 256 + t;
            int r = lin >> 3, c = (lin & 7) * 8;
            int ldsoff = (i * 256 + w * 64) * 8;   // wave-uniform, u16 units
            gload16(&A[(size_t)(m0 + r) * K + k0 + c], &As[ldsoff]);
            gload16(&Wt[(size_t)(n0 + r) * K + k0 + c], &Bs[ldsoff]);
        }
        __syncthreads();   // drains vmcnt -> staged data visible
#pragma unroll
        for (int ks = 0; ks < 64; ks += 32) {
            bf16x8 af[4], bf[4];
#pragma unroll
            for (int i = 0; i < 4; ++i) {
                af[i] = *(const bf16x8*)&As[(wm * 64 + i * 16 + l15) * 64 + ks + l4 * 8];
                bf[i] = *(const bf16x8*)&Bs[(wn * 64 + i * 16 + l15) * 64 + ks + l4 * 8];
            }
#pragma unroll
            for (int mi = 0; mi < 4; ++mi)
#pragma unroll
                for (int ni = 0; ni < 4; ++ni)
                    acc[mi][ni] = __builtin_amdgcn_mfma_f32_16x16x32_bf16(
                        af[mi], bf[ni], acc[mi][ni], 0, 0, 0);
        }
        __syncthreads();
    }

#pragma unroll
    for (int mi = 0; mi < 4; ++mi) {
#pragma unroll
        for (int ni = 0; ni < 4; ++ni) {
            int col = n0 + wn * 64 + ni * 16 + l15;
            float bn = bias[col];
            if (MODE == 2) {
                int token0 = m0 + wm * 64 + mi * 16 + l4 * 4;
                u16t o4[4];
#pragma unroll
                for (int r = 0; r < 4; ++r) o4[r] = f2bf(acc[mi][ni][r] + bn);
                int b = token0 >> 11, tb = token0 & (T_ - 1);
                int h = col >> 6, hd = col & 63;
                *(uint2*)&((u16t*)outp)[(((size_t)b * H_ + h) * HD_ + hd) * T_ + tb] =
                    *(const uint2*)o4;
            } else {
#pragma unroll
                for (int r = 0; r < 4; ++r) {
                    int row = m0 + wm * 64 + mi * 16 + l4 * 4 + r;
                    float v = (acc[mi][ni][r] + bn) * scale;
                    if (MODE == 1) ((float*)outp)[(size_t)row * N + col] = v;
                    else           ((u16t*)outp)[(size_t)row * N + col] = f2bf(v);
                }
            }
        }
    }
}

// ---------------- causal flash attention ----------------
// Plain launch_bounds(256): allocator free to use ~110 arch + acc regs -> no spill
// (R3-R5's 120-240MB scratch WRITE came from the (256,N) arch+acc cap).
// Grid 1024 linear; bh = lin&63 -> all 16 q-blocks of a bh land on XCD bh%8, whose
// L2 then holds its 8 bh x 512KB of K/V (re-reads become L2 hits).
// qtile pairing (q_idx&1 ? q/2 : 15-q/2): heavy-first dispatch, pair sums = 15.
__global__ __launch_bounds__(256) void attn_kernel(const u16t* __restrict__ Q,
                                                   const u16t* __restrict__ K,
                                                   const u16t* __restrict__ Vt,
                                                   u16t* __restrict__ O) {
    __shared__ u16t Ks[2][64 * 64];
    __shared__ u16t Vs[2][64 * 64];   // Vs[d][kv], swizzled

    const int t = threadIdx.x;
    const int lane = t & 63, w = t >> 6;
    const int l15 = lane & 15, l4 = lane >> 4;

    const int lin = blockIdx.x;
    const int bh = lin & 63;
    const int q_idx = lin >> 6;
    const int qtile = (q_idx & 1) ? (q_idx >> 1) : (15 - (q_idx >> 1));

    const size_t base = (size_t)(bh >> 4) * T_ * D_ + (size_t)(bh & 15) * HD_;
    const size_t vtbase = (size_t)bh * HD_ * T_;
    const int q0 = qtile * 128;
    const int qsub0 = q0 + w * 32;
    const int sw = l15 & 7;            // read-side XOR (row & 7)

    // staging: linear LDS dest; global source pre-swizzled with c16 ^= row&7
    auto stage = [&](int jt, int bufsel) {
#pragma unroll
        for (int c = 0; c < 2; ++c) {
            int i = c * 256 + t;
            int r = i >> 3, c16 = i & 7;
            int g16 = c16 ^ (r & 7);
            int ldsoff = (c * 256 + w * 64) * 8;   // u16 units, wave-uniform
            gload16(&K[base + (size_t)(jt * 64 + r) * D_ + g16 * 8], &Ks[bufsel][ldsoff]);
            gload16(&Vt[vtbase + (size_t)r * T_ + jt * 64 + g16 * 8], &Vs[bufsel][ldsoff]);
        }
    };

    bf16x8 qf[2][2];
#pragma unroll
    for (int qa = 0; qa < 2; ++qa) {
        const u16t* qp = &Q[base + (size_t)(qsub0 + qa * 16 + l15) * D_];
        qf[qa][0] = *(const bf16x8*)&qp[l4 * 8];
        qf[qa][1] = *(const bf16x8*)&qp[32 + l4 * 8];
    }

    f32x4 acc_o[2][4] = {};
    float mrun[2] = {-1e30f, -1e30f};
    float lrun[2] = {0.f, 0.f};

    const int njt = 2 * qtile + 2;
    stage(0, 0);

    for (int jt = 0; jt < njt; ++jt) {
        const int cur = jt & 1;
        const int kv0 = jt * 64;
        __syncthreads();                 // drains vmcnt: buf[cur] ready; guards buf reuse
        if (jt + 1 < njt) stage(jt + 1, cur ^ 1);

        if (kv0 <= qsub0 + 31) {         // skip fully-masked tail tiles (waves 0/1)
            const u16t* kb = Ks[cur];
            const u16t* vb = Vs[cur];

            bf16x8 pa[2][2];
#pragma unroll
            for (int qa = 0; qa < 2; ++qa) {
                f32x4 accs[4] = {};      // scoped: reused across qa (AGPR-resident)
                __builtin_amdgcn_s_setprio(1);
#pragma unroll
                for (int mt = 0; mt < 4; ++mt) {
                    const u16t* kr = &kb[(mt * 16 + l15) * 64];
                    bf16x8 kf0 = *(const bf16x8*)&kr[(l4 ^ sw) * 8];
                    bf16x8 kf1 = *(const bf16x8*)&kr[((4 + l4) ^ sw) * 8];
                    accs[mt] = __builtin_amdgcn_mfma_f32_16x16x32_bf16(kf0, qf[qa][0], accs[mt], 0, 0, 0);
                    accs[mt] = __builtin_amdgcn_mfma_f32_16x16x32_bf16(kf1, qf[qa][1], accs[mt], 0, 0, 0);
                }
                __builtin_amdgcn_s_setprio(0);

                const int qrow = qsub0 + qa * 16 + l15;
                if (kv0 + 63 > qsub0 + qa * 16) {   // diagonal-touching: causal mask
#pragma unroll
                    for (int mt = 0; mt < 4; ++mt)
#pragma unroll
                        for (int r = 0; r < 4; ++r)
                            if (kv0 + mt * 16 + l4 * 4 + r > qrow) accs[mt][r] = -1e30f;
                }

                float pmax = -1e30f;
#pragma unroll
                for (int mt = 0; mt < 4; ++mt)
#pragma unroll
                    for (int r = 0; r < 4; ++r) pmax = fmaxf(pmax, accs[mt][r]);
                pmax = fmaxf(pmax, __shfl_xor(pmax, 16));
                pmax = fmaxf(pmax, __shfl_xor(pmax, 32));

                // defer-rescale (THR=0, exact), base-2 domain
                if (!__all(pmax <= mrun[qa])) {
                    float mnew = fmaxf(mrun[qa], pmax);
                    float corr = exp2f(mrun[qa] - mnew);
                    lrun[qa] *= corr;
                    mrun[qa] = mnew;
#pragma unroll
                    for (int r = 0; r < 4; ++r) {
                        float f = __shfl(corr, l4 * 4 + r);
#pragma unroll
                        for (int nt = 0; nt < 4; ++nt) acc_o[qa][nt][r] *= f;
                    }
                }

                const float m = mrun[qa];
                float sm[4];
#pragma unroll
                for (int mt = 0; mt < 4; ++mt) {
                    float s = 0.f;
#pragma unroll
                    for (int r = 0; r < 4; ++r) {
                        float p = exp2f(accs[mt][r] - m);
                        s += p;
                        pa[qa][mt >> 1][(mt & 1) * 4 + r] = (__bf16)p;   // k-slot pi mapping
                    }
                    sm[mt] = s;
                }
                float psum = (sm[0] + sm[1]) + (sm[2] + sm[3]);
                psum += __shfl_xor(psum, 16);
                psum += __shfl_xor(psum, 32);
                lrun[qa] += psum;
            }

            // PV, k-slot permutation pi_s(l4,j) = 32s + (j>=4?16:0) + l4*4 + (j&3)
            __builtin_amdgcn_s_setprio(1);
#pragma unroll
            for (int s = 0; s < 2; ++s) {
#pragma unroll
                for (int nt = 0; nt < 4; ++nt) {
                    const u16t* vr = &vb[(nt * 16 + l15) * 64];
                    int o1 = s * 32 + l4 * 4, o2 = o1 + 16;
                    bf16x4 v0 = *(const bf16x4*)&vr[(((o1 >> 3) ^ sw) << 3) | (o1 & 7)];
                    bf16x4 v1 = *(const bf16x4*)&vr[(((o2 >> 3) ^ sw) << 3) | (o2 & 7)];
                    bf16x8 vf = __builtin_shufflevector(v0, v1, 0, 1, 2, 3, 4, 5, 6, 7);
                    acc_o[0][nt] = __builtin_amdgcn_mfma_f32_16x16x32_bf16(pa[0][s], vf, acc_o[0][nt], 0, 0, 0);
                    acc_o[1][nt] = __builtin_amdgcn_mfma_f32_16x16x32_bf16(pa[1][s], vf, acc_o[1][nt], 0, 0, 0);
                }
            }
            __builtin_amdgcn_s_setprio(0);
        }
    }

    // finalize: divide by l, store bf16
#pragma unroll
    for (int qa = 0; qa < 2; ++qa)
#pragma unroll
        for (int r = 0; r < 4; ++r) {
            float li = __shfl(lrun[qa], l4 * 4 + r);
            float inv = 1.f / li;
            int row = qsub0 + qa * 16 + l4 * 4 + r;
#pragma unroll
            for (int nt = 0; nt < 4; ++nt)
                O[base + (size_t)row * D_ + nt * 16 + l15] = f2bf(acc_o[qa][nt][r] * inv);
        }
}

extern "C" void kernel_launch(void* const* d_in, const int* in_sizes, int n_in,
                              void* d_out, int out_size, void* d_ws, size_t ws_size,
                              hipStream_t stream) {
    const float* x  = (const float*)d_in[0];
    const float* Wq = (const float*)d_in[1];
    const float* bq = (const float*)d_in[2];
    const float* Wk = (const float*)d_in[3];
    const float* bk = (const float*)d_in[4];
    const float* Wv = (const float*)d_in[5];
    const float* bv = (const float*)d_in[6];
    const float* Wp = (const float*)d_in[7];
    const float* bp = (const float*)d_in[8];
    float* out = (float*)d_out;

    u16t* ws = (u16t*)d_ws;
    const size_t XN = (size_t)M_TOT * D_;      // 8M elems
    u16t* xb  = ws;                            // x bf16; reused as attn output O
    u16t* q   = ws + XN;
    u16t* k   = ws + 2 * XN;
    u16t* vt  = ws + 3 * XN;                   // Vt[b][h][hd][t] (written by V-GEMM epilogue)
    u16t* wtq = ws + 4 * XN;
    u16t* wtk = wtq + (size_t)D_ * D_;
    u16t* wtv = wtk + (size_t)D_ * D_;
    u16t* wtp = wtv + (size_t)D_ * D_;
    u16t* o   = xb;                            // attn output reuses xb (dead after GEMMs)

    cvt_bf16_kernel<<<(int)(XN / 8 / 256), 256, 0, stream>>>(x, xb, (int)(XN / 8));
    transp_kernel<<<dim3(16, 16, 4), 256, 0, stream>>>(Wq, Wk, Wv, Wp, wtq, wtk, wtv, wtp);

    dim3 ggrid(M_TOT / 128, D_ / 128);
    // Q scale folds 1/sqrt(HD) * log2(e): softmax runs in base-2 domain
    gemm_bf16_kernel<0><<<ggrid, 256, 0, stream>>>(xb, wtq, bq, q, 0.125f * 1.44269504088896f);
    gemm_bf16_kernel<0><<<ggrid, 256, 0, stream>>>(xb, wtk, bk, k, 1.0f);
    gemm_bf16_kernel<2><<<ggrid, 256, 0, stream>>>(xb, wtv, bv, vt, 1.0f);  // fused V-transpose

    attn_kernel<<<dim3(1024), 256, 0, stream>>>(q, k, vt, o);

    gemm_bf16_kernel<1><<<ggrid, 256, 0, stream>>>(o, wtp, bp, out, 1.0f);
}

// Round 7
// 231.728 us; speedup vs baseline: 1.3513x; 1.0428x over previous
//
#include <hip/hip_runtime.h>
#include <hip/hip_bf16.h>
#include <stdint.h>

#define B_ 4
#define T_ 2048
#define D_ 1024
#define H_ 16
#define HD_ 64
#define M_TOT (B_ * T_)   // 8192

typedef unsigned short u16t;
typedef __bf16 bf16x4 __attribute__((ext_vector_type(4)));
typedef __bf16 bf16x8 __attribute__((ext_vector_type(8)));
typedef float f32x4 __attribute__((ext_vector_type(4)));

__device__ __forceinline__ u16t f2bf(float f) {
    union { float f; uint32_t u; } x; x.f = f;
    uint32_t r = x.u + 0x7fffu + ((x.u >> 16) & 1u);
    return (u16t)(r >> 16);
}

// async global -> LDS, 16B per lane; lds dest is wave-uniform base (+ lane*16 by HW)
__device__ __forceinline__ void gload16(const void* g, void* l) {
    __builtin_amdgcn_global_load_lds((const __attribute__((address_space(1))) void*)g,
                                     (__attribute__((address_space(3))) void*)l, 16, 0, 0);
}

// ---------------- convert x (fp32 -> bf16), 8 elems/thread ----------------
__global__ __launch_bounds__(256) void cvt_bf16_kernel(const float* __restrict__ in,
                                                       u16t* __restrict__ out, int n8) {
    int i = blockIdx.x * 256 + threadIdx.x;
    if (i >= n8) return;
    const float4* p = (const float4*)in + (size_t)i * 2;
    float4 a = p[0], b = p[1];
    u16t o[8] = {f2bf(a.x), f2bf(a.y), f2bf(a.z), f2bf(a.w),
                 f2bf(b.x), f2bf(b.y), f2bf(b.z), f2bf(b.w)};
    *(uint4*)(out + (size_t)i * 8) = *(const uint4*)o;
}

// ------------- transpose + convert W[k][n] fp32 -> Wt[n][k] bf16 -------------
__global__ __launch_bounds__(256) void transp_kernel(const float* __restrict__ W0,
                                                     const float* __restrict__ W1,
                                                     const float* __restrict__ W2,
                                                     const float* __restrict__ W3,
                                                     u16t* __restrict__ T0,
                                                     u16t* __restrict__ T1,
                                                     u16t* __restrict__ T2,
                                                     u16t* __restrict__ T3) {
    __shared__ u16t tile[64][65];
    const float* W; u16t* To;
    switch (blockIdx.z) {
        case 0: W = W0; To = T0; break;
        case 1: W = W1; To = T1; break;
        case 2: W = W2; To = T2; break;
        default: W = W3; To = T3; break;
    }
    int n0 = blockIdx.x * 64, k0 = blockIdx.y * 64;
    int t = threadIdx.x;
#pragma unroll
    for (int i = 0; i < 16; ++i) {
        int idx = i * 256 + t;
        int r = idx >> 6, c = idx & 63;
        tile[r][c] = f2bf(W[(size_t)(k0 + r) * D_ + n0 + c]);
    }
    __syncthreads();
#pragma unroll
    for (int i = 0; i < 16; ++i) {
        int idx = i * 256 + t;
        int r = idx >> 6, c = idx & 63;
        To[(size_t)(n0 + r) * D_ + k0 + c] = tile[c][r];
    }
}

// ---------------- bf16 GEMM (m97 structure: global_load_lds staging, linear LDS) ----
// MODE 0: bf16 row-major out. MODE 1: f32 row-major out. MODE 2: bf16 Vt[b][h][hd][t] out.
template <int MODE>
__global__ __launch_bounds__(256) void gemm_bf16_kernel(const u16t* __restrict__ A,
                                                        const u16t* __restrict__ Wt,
                                                        const float* __restrict__ bias,
                                                        void* __restrict__ outp,
                                                        float scale) {
    __shared__ u16t As[128 * 64];
    __shared__ u16t Bs[128 * 64];
    const int t = threadIdx.x;
    const int lane = t & 63, w = t >> 6;
    const int wm = w >> 1, wn = w & 1;
    const int l15 = lane & 15, l4 = lane >> 4;
    const int m0 = blockIdx.x * 128, n0 = blockIdx.y * 128;
    const int K = D_, N = D_;

    f32x4 acc[4][4] = {};

    for (int k0 = 0; k0 < K; k0 += 64) {
#pragma unroll
        for (int i = 0; i < 4; ++i) {
            int lin = i * 256 + t;
            int r = lin >> 3, c = (lin & 7) * 8;
            int ldsoff = (i * 256 + w * 64) * 8;   // wave-uniform, u16 units
            gload16(&A[(size_t)(m0 + r) * K + k0 + c], &As[ldsoff]);
            gload16(&Wt[(size_t)(n0 + r) * K + k0 + c], &Bs[ldsoff]);
        }
        __syncthreads();   // drains vmcnt -> staged data visible
#pragma unroll
        for (int ks = 0; ks < 64; ks += 32) {
            bf16x8 af[4], bf[4];
#pragma unroll
            for (int i = 0; i < 4; ++i) {
                af[i] = *(const bf16x8*)&As[(wm * 64 + i * 16 + l15) * 64 + ks + l4 * 8];
                bf[i] = *(const bf16x8*)&Bs[(wn * 64 + i * 16 + l15) * 64 + ks + l4 * 8];
            }
#pragma unroll
            for (int mi = 0; mi < 4; ++mi)
#pragma unroll
                for (int ni = 0; ni < 4; ++ni)
                    acc[mi][ni] = __builtin_amdgcn_mfma_f32_16x16x32_bf16(
                        af[mi], bf[ni], acc[mi][ni], 0, 0, 0);
        }
        __syncthreads();
    }

#pragma unroll
    for (int mi = 0; mi < 4; ++mi) {
#pragma unroll
        for (int ni = 0; ni < 4; ++ni) {
            int col = n0 + wn * 64 + ni * 16 + l15;
            float bn = bias[col];
            if (MODE == 2) {
                int token0 = m0 + wm * 64 + mi * 16 + l4 * 4;
                u16t o4[4];
#pragma unroll
                for (int r = 0; r < 4; ++r) o4[r] = f2bf(acc[mi][ni][r] + bn);
                int b = token0 >> 11, tb = token0 & (T_ - 1);
                int h = col >> 6, hd = col & 63;
                *(uint2*)&((u16t*)outp)[(((size_t)b * H_ + h) * HD_ + hd) * T_ + tb] =
                    *(const uint2*)o4;
            } else {
#pragma unroll
                for (int r = 0; r < 4; ++r) {
                    int row = m0 + wm * 64 + mi * 16 + l4 * 4 + r;
                    float v = (acc[mi][ni][r] + bn) * scale;
                    if (MODE == 1) ((float*)outp)[(size_t)row * N + col] = v;
                    else           ((u16t*)outp)[(size_t)row * N + col] = f2bf(v);
                }
            }
        }
    }
}

// ---------------- causal flash attention ----------------
// Grid 1024 linear; bh = lin&63 -> all 16 q-blocks of a bh land on XCD bh%8 (L2-resident
// K/V; R6 verified FETCH 227->32MB). Co-resident blocks on one CU are stride-256 in lin,
// i.e. q_idx classes {r,r+4,r+8,r+12}; perm[] balances each class to sum 30 k-tile iters
// and is descending in dispatch order (heavy first, short tail). R6's parity pairing put
// all-heavy/all-light classes on CUs -> 16.5% occupancy.
__global__ __launch_bounds__(256) void attn_kernel(const u16t* __restrict__ Q,
                                                   const u16t* __restrict__ K,
                                                   const u16t* __restrict__ Vt,
                                                   u16t* __restrict__ O) {
    __shared__ u16t Ks[2][64 * 64];
    __shared__ u16t Vs[2][64 * 64];   // Vs[d][kv], swizzled

    const int t = threadIdx.x;
    const int lane = t & 63, w = t >> 6;
    const int l15 = lane & 15, l4 = lane >> 4;

    const int lin = blockIdx.x;
    const int bh = lin & 63;
    const int q_idx = lin >> 6;
    const int perm[16] = {15,12,14,13, 8,11,9,10, 4,7,5,6, 3,0,2,1};
    const int qtile = perm[q_idx];

    const size_t base = (size_t)(bh >> 4) * T_ * D_ + (size_t)(bh & 15) * HD_;
    const size_t vtbase = (size_t)bh * HD_ * T_;
    const int q0 = qtile * 128;
    const int qsub0 = q0 + w * 32;
    const int sw = l15 & 7;            // read-side XOR (row & 7)

    // staging: linear LDS dest; global source pre-swizzled with c16 ^= row&7
    auto stage = [&](int jt, int bufsel) {
#pragma unroll
        for (int c = 0; c < 2; ++c) {
            int i = c * 256 + t;
            int r = i >> 3, c16 = i & 7;
            int g16 = c16 ^ (r & 7);
            int ldsoff = (c * 256 + w * 64) * 8;   // u16 units, wave-uniform
            gload16(&K[base + (size_t)(jt * 64 + r) * D_ + g16 * 8], &Ks[bufsel][ldsoff]);
            gload16(&Vt[vtbase + (size_t)r * T_ + jt * 64 + g16 * 8], &Vs[bufsel][ldsoff]);
        }
    };

    bf16x8 qf[2][2];
#pragma unroll
    for (int qa = 0; qa < 2; ++qa) {
        const u16t* qp = &Q[base + (size_t)(qsub0 + qa * 16 + l15) * D_];
        qf[qa][0] = *(const bf16x8*)&qp[l4 * 8];
        qf[qa][1] = *(const bf16x8*)&qp[32 + l4 * 8];
    }

    f32x4 acc_o[2][4] = {};
    float mrun[2] = {-1e30f, -1e30f};
    float lrun[2] = {0.f, 0.f};

    const int njt = 2 * qtile + 2;
    stage(0, 0);

    for (int jt = 0; jt < njt; ++jt) {
        const int cur = jt & 1;
        const int kv0 = jt * 64;
        __syncthreads();                 // drains vmcnt: buf[cur] ready; guards buf reuse
        if (jt + 1 < njt) stage(jt + 1, cur ^ 1);

        if (kv0 <= qsub0 + 31) {         // skip fully-masked tail tiles (waves 0/1)
            const u16t* kb = Ks[cur];
            const u16t* vb = Vs[cur];

            bf16x8 pa[2][2];
#pragma unroll
            for (int qa = 0; qa < 2; ++qa) {
                f32x4 accs[4] = {};      // scoped: reused across qa (AGPR-resident)
                __builtin_amdgcn_s_setprio(1);
#pragma unroll
                for (int mt = 0; mt < 4; ++mt) {
                    const u16t* kr = &kb[(mt * 16 + l15) * 64];
                    bf16x8 kf0 = *(const bf16x8*)&kr[(l4 ^ sw) * 8];
                    bf16x8 kf1 = *(const bf16x8*)&kr[((4 + l4) ^ sw) * 8];
                    accs[mt] = __builtin_amdgcn_mfma_f32_16x16x32_bf16(kf0, qf[qa][0], accs[mt], 0, 0, 0);
                    accs[mt] = __builtin_amdgcn_mfma_f32_16x16x32_bf16(kf1, qf[qa][1], accs[mt], 0, 0, 0);
                }
                __builtin_amdgcn_s_setprio(0);

                const int qrow = qsub0 + qa * 16 + l15;
                if (kv0 + 63 > qsub0 + qa * 16) {   // diagonal-touching: causal mask
#pragma unroll
                    for (int mt = 0; mt < 4; ++mt)
#pragma unroll
                        for (int r = 0; r < 4; ++r)
                            if (kv0 + mt * 16 + l4 * 4 + r > qrow) accs[mt][r] = -1e30f;
                }

                float pmax = -1e30f;
#pragma unroll
                for (int mt = 0; mt < 4; ++mt)
#pragma unroll
                    for (int r = 0; r < 4; ++r) pmax = fmaxf(pmax, accs[mt][r]);
                pmax = fmaxf(pmax, __shfl_xor(pmax, 16));
                pmax = fmaxf(pmax, __shfl_xor(pmax, 32));

                // defer-rescale (THR=0, exact), base-2 domain
                if (!__all(pmax <= mrun[qa])) {
                    float mnew = fmaxf(mrun[qa], pmax);
                    float corr = exp2f(mrun[qa] - mnew);
                    lrun[qa] *= corr;
                    mrun[qa] = mnew;
#pragma unroll
                    for (int r = 0; r < 4; ++r) {
                        float f = __shfl(corr, l4 * 4 + r);
#pragma unroll
                        for (int nt = 0; nt < 4; ++nt) acc_o[qa][nt][r] *= f;
                    }
                }

                const float m = mrun[qa];
                float sm[4];
#pragma unroll
                for (int mt = 0; mt < 4; ++mt) {
                    float s = 0.f;
#pragma unroll
                    for (int r = 0; r < 4; ++r) {
                        float p = exp2f(accs[mt][r] - m);
                        s += p;
                        pa[qa][mt >> 1][(mt & 1) * 4 + r] = (__bf16)p;   // k-slot pi mapping
                    }
                    sm[mt] = s;
                }
                float psum = (sm[0] + sm[1]) + (sm[2] + sm[3]);
                psum += __shfl_xor(psum, 16);
                psum += __shfl_xor(psum, 32);
                lrun[qa] += psum;
            }

            // PV, k-slot permutation pi_s(l4,j) = 32s + (j>=4?16:0) + l4*4 + (j&3)
            __builtin_amdgcn_s_setprio(1);
#pragma unroll
            for (int s = 0; s < 2; ++s) {
#pragma unroll
                for (int nt = 0; nt < 4; ++nt) {
                    const u16t* vr = &vb[(nt * 16 + l15) * 64];
                    int o1 = s * 32 + l4 * 4, o2 = o1 + 16;
                    bf16x4 v0 = *(const bf16x4*)&vr[(((o1 >> 3) ^ sw) << 3) | (o1 & 7)];
                    bf16x4 v1 = *(const bf16x4*)&vr[(((o2 >> 3) ^ sw) << 3) | (o2 & 7)];
                    bf16x8 vf = __builtin_shufflevector(v0, v1, 0, 1, 2, 3, 4, 5, 6, 7);
                    acc_o[0][nt] = __builtin_amdgcn_mfma_f32_16x16x32_bf16(pa[0][s], vf, acc_o[0][nt], 0, 0, 0);
                    acc_o[1][nt] = __builtin_amdgcn_mfma_f32_16x16x32_bf16(pa[1][s], vf, acc_o[1][nt], 0, 0, 0);
                }
            }
            __builtin_amdgcn_s_setprio(0);
        }
    }

    // finalize: divide by l, store bf16
#pragma unroll
    for (int qa = 0; qa < 2; ++qa)
#pragma unroll
        for (int r = 0; r < 4; ++r) {
            float li = __shfl(lrun[qa], l4 * 4 + r);
            float inv = 1.f / li;
            int row = qsub0 + qa * 16 + l4 * 4 + r;
#pragma unroll
            for (int nt = 0; nt < 4; ++nt)
                O[base + (size_t)row * D_ + nt * 16 + l15] = f2bf(acc_o[qa][nt][r] * inv);
        }
}

extern "C" void kernel_launch(void* const* d_in, const int* in_sizes, int n_in,
                              void* d_out, int out_size, void* d_ws, size_t ws_size,
                              hipStream_t stream) {
    const float* x  = (const float*)d_in[0];
    const float* Wq = (const float*)d_in[1];
    const float* bq = (const float*)d_in[2];
    const float* Wk = (const float*)d_in[3];
    const float* bk = (const float*)d_in[4];
    const float* Wv = (const float*)d_in[5];
    const float* bv = (const float*)d_in[6];
    const float* Wp = (const float*)d_in[7];
    const float* bp = (const float*)d_in[8];
    float* out = (float*)d_out;

    u16t* ws = (u16t*)d_ws;
    const size_t XN = (size_t)M_TOT * D_;      // 8M elems
    u16t* xb  = ws;                            // x bf16; reused as attn output O
    u16t* q   = ws + XN;
    u16t* k   = ws + 2 * XN;
    u16t* vt  = ws + 3 * XN;                   // Vt[b][h][hd][t] (written by V-GEMM epilogue)
    u16t* wtq = ws + 4 * XN;
    u16t* wtk = wtq + (size_t)D_ * D_;
    u16t* wtv = wtk + (size_t)D_ * D_;
    u16t* wtp = wtv + (size_t)D_ * D_;
    u16t* o   = xb;                            // attn output reuses xb (dead after GEMMs)

    cvt_bf16_kernel<<<(int)(XN / 8 / 256), 256, 0, stream>>>(x, xb, (int)(XN / 8));
    transp_kernel<<<dim3(16, 16, 4), 256, 0, stream>>>(Wq, Wk, Wv, Wp, wtq, wtk, wtv, wtp);

    dim3 ggrid(M_TOT / 128, D_ / 128);
    // Q scale folds 1/sqrt(HD) * log2(e): softmax runs in base-2 domain
    gemm_bf16_kernel<0><<<ggrid, 256, 0, stream>>>(xb, wtq, bq, q, 0.125f * 1.44269504088896f);
    gemm_bf16_kernel<0><<<ggrid, 256, 0, stream>>>(xb, wtk, bk, k, 1.0f);
    gemm_bf16_kernel<2><<<ggrid, 256, 0, stream>>>(xb, wtv, bv, vt, 1.0f);  // fused V-transpose

    attn_kernel<<<dim3(1024), 256, 0, stream>>>(q, k, vt, o);

    gemm_bf16_kernel<1><<<ggrid, 256, 0, stream>>>(o, wtp, bp, out, 1.0f);
}

// Round 9
// 209.829 us; speedup vs baseline: 1.4923x; 1.1044x over previous
//
#include <hip/hip_runtime.h>
#include <hip/hip_bf16.h>
#include <stdint.h>

#define B_ 4
#define T_ 2048
#define D_ 1024
#define H_ 16
#define HD_ 64
#define M_TOT (B_ * T_)   // 8192

typedef unsigned short u16t;
typedef __bf16 bf16x4 __attribute__((ext_vector_type(4)));
typedef __bf16 bf16x8 __attribute__((ext_vector_type(8)));
typedef float f32x4 __attribute__((ext_vector_type(4)));
typedef float f32x16 __attribute__((ext_vector_type(16)));

__device__ __forceinline__ u16t f2bf(float f) {
    union { float f; uint32_t u; } x; x.f = f;
    uint32_t r = x.u + 0x7fffu + ((x.u >> 16) & 1u);
    return (u16t)(r >> 16);
}

// async global -> LDS, 16B per lane; lds dest is wave-uniform base (+ lane*16 by HW)
__device__ __forceinline__ void gload16(const void* g, void* l) {
    __builtin_amdgcn_global_load_lds((const __attribute__((address_space(1))) void*)g,
                                     (__attribute__((address_space(3))) void*)l, 16, 0, 0);
}

// ---------------- convert x (fp32 -> bf16), 8 elems/thread ----------------
__global__ __launch_bounds__(256) void cvt_bf16_kernel(const float* __restrict__ in,
                                                       u16t* __restrict__ out, int n8) {
    int i = blockIdx.x * 256 + threadIdx.x;
    if (i >= n8) return;
    const float4* p = (const float4*)in + (size_t)i * 2;
    float4 a = p[0], b = p[1];
    u16t o[8] = {f2bf(a.x), f2bf(a.y), f2bf(a.z), f2bf(a.w),
                 f2bf(b.x), f2bf(b.y), f2bf(b.z), f2bf(b.w)};
    *(uint4*)(out + (size_t)i * 8) = *(const uint4*)o;
}

// ------------- transpose + convert W[k][n] fp32 -> Wt[n][k] bf16 -------------
__global__ __launch_bounds__(256) void transp_kernel(const float* __restrict__ W0,
                                                     const float* __restrict__ W1,
                                                     const float* __restrict__ W2,
                                                     const float* __restrict__ W3,
                                                     u16t* __restrict__ T0,
                                                     u16t* __restrict__ T1,
                                                     u16t* __restrict__ T2,
                                                     u16t* __restrict__ T3) {
    __shared__ u16t tile[64][65];
    const float* W; u16t* To;
    switch (blockIdx.z) {
        case 0: W = W0; To = T0; break;
        case 1: W = W1; To = T1; break;
        case 2: W = W2; To = T2; break;
        default: W = W3; To = T3; break;
    }
    int n0 = blockIdx.x * 64, k0 = blockIdx.y * 64;
    int t = threadIdx.x;
#pragma unroll
    for (int i = 0; i < 16; ++i) {
        int idx = i * 256 + t;
        int r = idx >> 6, c = idx & 63;
        tile[r][c] = f2bf(W[(size_t)(k0 + r) * D_ + n0 + c]);
    }
    __syncthreads();
#pragma unroll
    for (int i = 0; i < 16; ++i) {
        int idx = i * 256 + t;
        int r = idx >> 6, c = idx & 63;
        To[(size_t)(n0 + r) * D_ + k0 + c] = tile[c][r];
    }
}

// ---------------- bf16 GEMM (m97 structure: global_load_lds staging, linear LDS) ----
// MODE 0: bf16 row-major out. MODE 1: f32 row-major out. MODE 2: bf16 Vt[b][h][hd][t] out.
template <int MODE>
__global__ __launch_bounds__(256) void gemm_bf16_kernel(const u16t* __restrict__ A,
                                                        const u16t* __restrict__ Wt,
                                                        const float* __restrict__ bias,
                                                        void* __restrict__ outp,
                                                        float scale) {
    __shared__ u16t As[128 * 64];
    __shared__ u16t Bs[128 * 64];
    const int t = threadIdx.x;
    const int lane = t & 63, w = t >> 6;
    const int wm = w >> 1, wn = w & 1;
    const int l15 = lane & 15, l4 = lane >> 4;
    const int m0 = blockIdx.x * 128, n0 = blockIdx.y * 128;
    const int K = D_, N = D_;

    f32x4 acc[4][4] = {};

    for (int k0 = 0; k0 < K; k0 += 64) {
#pragma unroll
        for (int i = 0; i < 4; ++i) {
            int lin = i * 256 + t;
            int r = lin >> 3, c = (lin & 7) * 8;
            int ldsoff = (i * 256 + w * 64) * 8;   // wave-uniform, u16 units
            gload16(&A[(size_t)(m0 + r) * K + k0 + c], &As[ldsoff]);
            gload16(&Wt[(size_t)(n0 + r) * K + k0 + c], &Bs[ldsoff]);
        }
        __syncthreads();   // drains vmcnt -> staged data visible
#pragma unroll
        for (int ks = 0; ks < 64; ks += 32) {
            bf16x8 af[4], bf[4];
#pragma unroll
            for (int i = 0; i < 4; ++i) {
                af[i] = *(const bf16x8*)&As[(wm * 64 + i * 16 + l15) * 64 + ks + l4 * 8];
                bf[i] = *(const bf16x8*)&Bs[(wn * 64 + i * 16 + l15) * 64 + ks + l4 * 8];
            }
#pragma unroll
            for (int mi = 0; mi < 4; ++mi)
#pragma unroll
                for (int ni = 0; ni < 4; ++ni)
                    acc[mi][ni] = __builtin_amdgcn_mfma_f32_16x16x32_bf16(
                        af[mi], bf[ni], acc[mi][ni], 0, 0, 0);
        }
        __syncthreads();
    }

#pragma unroll
    for (int mi = 0; mi < 4; ++mi) {
#pragma unroll
        for (int ni = 0; ni < 4; ++ni) {
            int col = n0 + wn * 64 + ni * 16 + l15;
            float bn = bias[col];
            if (MODE == 2) {
                int token0 = m0 + wm * 64 + mi * 16 + l4 * 4;
                u16t o4[4];
#pragma unroll
                for (int r = 0; r < 4; ++r) o4[r] = f2bf(acc[mi][ni][r] + bn);
                int b = token0 >> 11, tb = token0 & (T_ - 1);
                int h = col >> 6, hd = col & 63;
                *(uint2*)&((u16t*)outp)[(((size_t)b * H_ + h) * HD_ + hd) * T_ + tb] =
                    *(const uint2*)o4;
            } else {
#pragma unroll
                for (int r = 0; r < 4; ++r) {
                    int row = m0 + wm * 64 + mi * 16 + l4 * 4 + r;
                    float v = (acc[mi][ni][r] + bn) * scale;
                    if (MODE == 1) ((float*)outp)[(size_t)row * N + col] = v;
                    else           ((u16t*)outp)[(size_t)row * N + col] = f2bf(v);
                }
            }
        }
    }
}

// ---------------- causal flash attention (32x32x16 MFMA, O^T epilogue) ----------------
// Per wave: 32 q rows. S^T via mfma(K, Q): lane col q = l31, rows kv per C/D map
// (r&3)+8*(r>>2)+4*l5. Softmax reduce = 1 shfl_xor(32). PV computes O^T = V^T @ P^T
// with k-slot permutation sigma(l5,j,m)=4l5+(j&3)+8(j>>2)+16(m&1)+32(m>>1):
// P^T B-frag = lane's own exp(S) regs slice [8*(m&1)..+7] of half m>>1 -> zero cross-lane;
// O^T cols = q = l31 -> corr rescale and 1/l are plain per-lane muls (no broadcasts).
// Coalesced O store via per-wave LDS transpose at the end (reuses K/V buffers).
__global__ __launch_bounds__(256) void attn_kernel(const u16t* __restrict__ Q,
                                                   const u16t* __restrict__ K,
                                                   const u16t* __restrict__ Vt,
                                                   u16t* __restrict__ O) {
    __shared__ u16t smem[16384];   // Ks[2]=+0/+4096, Vs[2]=+8192/+12288 (u16 units)

    const int t = threadIdx.x;
    const int lane = t & 63, w = t >> 6;
    const int l31 = lane & 31, l5 = lane >> 5;

    const int lin = blockIdx.x;
    const int bh = lin & 63;                  // XCD-local K/V (R6: FETCH 227->32MB)
    const int q_idx = lin >> 6;
    const int perm[16] = {15,12,14,13, 8,11,9,10, 4,7,5,6, 3,0,2,1};  // class sums 30
    const int qtile = perm[q_idx];

    const size_t base = (size_t)(bh >> 4) * T_ * D_ + (size_t)(bh & 15) * HD_;
    const size_t vtbase = (size_t)bh * HD_ * T_;
    const int q0 = qtile * 128;
    const int qsub0 = q0 + w * 32;
    const int sw = l31 & 7;                   // LDS read-side XOR (row & 7)

    // staging source pointers (pre-swizzled global column granule)
    const int sr = t >> 3, sc16 = t & 7;
    const int g16 = sc16 ^ (sr & 7);
    const u16t* kp = &K[base + (size_t)sr * D_ + g16 * 8];
    const u16t* vp = &Vt[vtbase + (size_t)sr * T_ + g16 * 8];

    auto stage = [&](int jt, int buf) {
        const u16t* kq = kp + (size_t)jt * 64 * D_;
        const u16t* vq = vp + (size_t)jt * 64;
        u16t* kd = smem + buf * 4096;
        u16t* vd = smem + 8192 + buf * 4096;
#pragma unroll
        for (int c = 0; c < 2; ++c) {
            gload16(kq + (size_t)c * 32 * D_, kd + c * 2048 + w * 512);
            gload16(vq + (size_t)c * 32 * T_, vd + c * 2048 + w * 512);
        }
    };

    // Q fragments: B-operand, col q = l31, k(d) = ks*16 + l5*8 + j
    const u16t* qp = &Q[base + (size_t)(qsub0 + l31) * D_ + l5 * 8];
    bf16x8 qf[4];
#pragma unroll
    for (int ks = 0; ks < 4; ++ks) qf[ks] = *(const bf16x8*)&qp[ks * 16];

    f32x16 acc_oT[2] = {};   // O^T[d = dh*32 + (r&3)+8(r>>2)+4l5][q = l31]
    float mrun = -1e30f, lrun = 0.f;

    const int njt = 2 * qtile + 2;
    stage(0, 0);

    for (int jt = 0; jt < njt; ++jt) {
        const int cur = jt & 1;
        const int kv0 = jt * 64;
        __syncthreads();                 // drains vmcnt: buf[cur] ready; guards buf reuse
        if (jt + 1 < njt) stage(jt + 1, cur ^ 1);

        if (kv0 <= qsub0 + 31) {         // skip fully-masked tiles
            const u16t* kb = smem + cur * 4096;
            const u16t* vb = smem + 8192 + cur * 4096;

            // QK^T: accs[half] = S^T rows kv0+half*32+..., col q=l31. K-tile read ONCE.
            f32x16 accs[2] = {};
            __builtin_amdgcn_s_setprio(1);
#pragma unroll
            for (int half = 0; half < 2; ++half) {
                const u16t* kr = kb + (half * 32 + l31) * 64;
#pragma unroll
                for (int ks = 0; ks < 4; ++ks) {
                    bf16x8 kf = *(const bf16x8*)&kr[((ks * 2 + l5) ^ sw) * 8];
                    accs[half] = __builtin_amdgcn_mfma_f32_32x32x16_bf16(
                        kf, qf[ks], accs[half], 0, 0, 0);
                }
            }
            __builtin_amdgcn_s_setprio(0);

            const int qrow = qsub0 + l31;
            if (kv0 + 63 > qsub0) {      // diagonal-touching: causal mask
#pragma unroll
                for (int half = 0; half < 2; ++half)
#pragma unroll
                    for (int r = 0; r < 16; ++r) {
                        int kv = kv0 + half * 32 + (r & 3) + 8 * (r >> 2) + 4 * l5;
                        if (kv > qrow) accs[half][r] = -1e30f;
                    }
            }

            // row max: 31 in-lane fmax + 1 shfl (l5 partner holds same q)
            float pmax = -1e30f;
#pragma unroll
            for (int half = 0; half < 2; ++half)
#pragma unroll
                for (int r = 0; r < 16; ++r) pmax = fmaxf(pmax, accs[half][r]);
            pmax = fmaxf(pmax, __shfl_xor(pmax, 32));

            // defer-rescale (THR=0, exact), base-2 domain; per-lane (q=l31) -> no broadcast
            if (!__all(pmax <= mrun)) {
                float mnew = fmaxf(mrun, pmax);
                float corr = exp2f(mrun - mnew);
                lrun *= corr;
                mrun = mnew;
                acc_oT[0] *= corr;
                acc_oT[1] *= corr;
            }

            // exp + pack P^T B-frags + psum
            float psum = 0.f;
            bf16x8 pb[4];
#pragma unroll
            for (int half = 0; half < 2; ++half)
#pragma unroll
                for (int r = 0; r < 16; ++r) {
                    float p = exp2f(accs[half][r] - mrun);
                    psum += p;
                    pb[half * 2 + (r >> 3)][r & 7] = (__bf16)p;
                }
            psum += __shfl_xor(psum, 32);
            lrun += psum;

            // PV: O^T += V^T @ P^T, sigma k-slots; af = 2 b64 per (dh,m)
            __builtin_amdgcn_s_setprio(1);
#pragma unroll
            for (int dh = 0; dh < 2; ++dh) {
                const u16t* vr = vb + (dh * 32 + l31) * 64;
#pragma unroll
                for (int m = 0; m < 4; ++m) {
                    int g = 2 * (m & 1) + 4 * (m >> 1);
                    bf16x4 v0 = *(const bf16x4*)&vr[((g ^ sw) << 3) + 4 * l5];
                    bf16x4 v1 = *(const bf16x4*)&vr[(((g + 1) ^ sw) << 3) + 4 * l5];
                    bf16x8 af = __builtin_shufflevector(v0, v1, 0, 1, 2, 3, 4, 5, 6, 7);
                    acc_oT[dh] = __builtin_amdgcn_mfma_f32_32x32x16_bf16(
                        af, pb[m], acc_oT[dh], 0, 0, 0);
                }
            }
            __builtin_amdgcn_s_setprio(0);
        }
    }

    // epilogue: per-wave LDS transpose O^T -> O, coalesced b128 stores
    __syncthreads();                      // all waves done reading K/V buffers
    float inv = 1.f / lrun;
    u16t* ot = smem + w * 2304;           // [32 q][72 pad]
#pragma unroll
    for (int dh = 0; dh < 2; ++dh)
#pragma unroll
        for (int r = 0; r < 16; ++r) {
            int d = dh * 32 + (r & 3) + 8 * (r >> 2) + 4 * l5;
            ot[l31 * 72 + d] = f2bf(acc_oT[dh][r] * inv);
        }
    __syncthreads();                      // per-wave data, but cheap + safe drain
#pragma unroll
    for (int p = 0; p < 4; ++p) {
        int idx = p * 64 + lane;
        int row = idx >> 3, c8 = (idx & 7) * 8;
        *(uint4*)&O[base + (size_t)(qsub0 + row) * D_ + c8] = *(const uint4*)&ot[row * 72 + c8];
    }
}

extern "C" void kernel_launch(void* const* d_in, const int* in_sizes, int n_in,
                              void* d_out, int out_size, void* d_ws, size_t ws_size,
                              hipStream_t stream) {
    const float* x  = (const float*)d_in[0];
    const float* Wq = (const float*)d_in[1];
    const float* bq = (const float*)d_in[2];
    const float* Wk = (const float*)d_in[3];
    const float* bk = (const float*)d_in[4];
    const float* Wv = (const float*)d_in[5];
    const float* bv = (const float*)d_in[6];
    const float* Wp = (const float*)d_in[7];
    const float* bp = (const float*)d_in[8];
    float* out = (float*)d_out;

    u16t* ws = (u16t*)d_ws;
    const size_t XN = (size_t)M_TOT * D_;      // 8M elems
    u16t* xb  = ws;                            // x bf16; reused as attn output O
    u16t* q   = ws + XN;
    u16t* k   = ws + 2 * XN;
    u16t* vt  = ws + 3 * XN;                   // Vt[b][h][hd][t] (written by V-GEMM epilogue)
    u16t* wtq = ws + 4 * XN;
    u16t* wtk = wtq + (size_t)D_ * D_;
    u16t* wtv = wtk + (size_t)D_ * D_;
    u16t* wtp = wtv + (size_t)D_ * D_;
    u16t* o   = xb;                            // attn output reuses xb (dead after GEMMs)

    cvt_bf16_kernel<<<(int)(XN / 8 / 256), 256, 0, stream>>>(x, xb, (int)(XN / 8));
    transp_kernel<<<dim3(16, 16, 4), 256, 0, stream>>>(Wq, Wk, Wv, Wp, wtq, wtk, wtv, wtp);

    dim3 ggrid(M_TOT / 128, D_ / 128);
    // Q scale folds 1/sqrt(HD) * log2(e): softmax runs in base-2 domain
    gemm_bf16_kernel<0><<<ggrid, 256, 0, stream>>>(xb, wtq, bq, q, 0.125f * 1.44269504088896f);
    gemm_bf16_kernel<0><<<ggrid, 256, 0, stream>>>(xb, wtk, bk, k, 1.0f);
    gemm_bf16_kernel<2><<<ggrid, 256, 0, stream>>>(xb, wtv, bv, vt, 1.0f);  // fused V-transpose

    attn_kernel<<<dim3(1024), 256, 0, stream>>>(q, k, vt, o);

    gemm_bf16_kernel<1><<<ggrid, 256, 0, stream>>>(o, wtp, bp, out, 1.0f);
}